// Round 1
// baseline (815.096 us; speedup 1.0000x reference)
//
#include <hip/hip_runtime.h>
#include <hip/hip_bf16.h>
#include <math.h>

// Problem constants: B=2, C=128, T=512, F=64 -> N=B*F=128 sequences, NT=65536 rows.
// GRU: G=4 groups, D=32, 3D=96. MHA: H=4 heads, Dh=32, window=100.
// Workspace layout (needs ~100.8 MB):
//   seq  fp32 [65536][128]  @ 0          (33,554,432 B)  residual stream
//   tmpb bf16 [65536][128]  @ 33554432   (16,777,216 B)  ln1/ln2/attn-out
//   big  bf16 [65536][384]  @ 50331648   (50,331,648 B)  xp (grouped: [(n,t,g)][96]) then qkv
//   wbuf bf16 weights       @ 100663296  (~137 KB)

typedef __attribute__((ext_vector_type(8))) short short8;
typedef __attribute__((ext_vector_type(4))) float f32x4;

__device__ __forceinline__ float bflo(unsigned int u) { return __uint_as_float(u << 16); }
__device__ __forceinline__ float bfhi(unsigned int u) { return __uint_as_float(u & 0xffff0000u); }
__device__ __forceinline__ float bf2f(unsigned short u) { return __uint_as_float(((unsigned int)u) << 16); }
__device__ __forceinline__ unsigned short f2bf(float f) {
  __hip_bfloat16 h = __float2bfloat16(f);
  return *reinterpret_cast<unsigned short*>(&h);
}

// ---------------- weight fp32 -> bf16 ----------------
__global__ void cvt_kernel(const float* __restrict__ s, unsigned short* __restrict__ d, int n) {
  int i = blockIdx.x * 256 + threadIdx.x;
  if (i < n) d[i] = f2bf(s[i]);
}

// ---------------- transpose x[B,C,T,F] -> seq[(b*64+f)][t][c] ----------------
__global__ __launch_bounds__(256) void transpose_in_kernel(const float* __restrict__ x, float* __restrict__ seq) {
  __shared__ float tile[128 * 65];
  int b = blockIdx.x >> 9;
  int t = blockIdx.x & 511;
  for (int i = threadIdx.x; i < 128 * 64; i += 256) {
    int c = i >> 6, f = i & 63;
    tile[c * 65 + f] = x[(((size_t)(b * 128 + c)) * 512 + t) * 64 + f];
  }
  __syncthreads();
  for (int i = threadIdx.x; i < 64 * 128; i += 256) {
    int f = i >> 7, c = i & 127;
    seq[(((size_t)(b * 64 + f)) * 512 + t) * 128 + c] = tile[c * 65 + f];
  }
}

__global__ __launch_bounds__(256) void transpose_out_kernel(const float* __restrict__ seq, float* __restrict__ out) {
  __shared__ float tile[128 * 65];
  int b = blockIdx.x >> 9;
  int t = blockIdx.x & 511;
  for (int i = threadIdx.x; i < 64 * 128; i += 256) {
    int f = i >> 7, c = i & 127;
    tile[c * 65 + f] = seq[(((size_t)(b * 64 + f)) * 512 + t) * 128 + c];
  }
  __syncthreads();
  for (int i = threadIdx.x; i < 128 * 64; i += 256) {
    int c = i >> 6, f = i & 63;
    out[(((size_t)(b * 128 + c)) * 512 + t) * 64 + f] = tile[c * 65 + f];
  }
}

// ---------------- layernorm over C=128, fp32 in -> bf16 out ----------------
__global__ __launch_bounds__(256) void ln_kernel(const float* __restrict__ in, const float* __restrict__ g,
                                                 const float* __restrict__ b, unsigned short* __restrict__ out) {
  int row = blockIdx.x * 4 + (threadIdx.x >> 6);
  int lane = threadIdx.x & 63;
  float2 v = ((const float2*)(in + (size_t)row * 128))[lane];
  float s = v.x + v.y, ss = v.x * v.x + v.y * v.y;
  #pragma unroll
  for (int off = 32; off > 0; off >>= 1) {
    s += __shfl_xor(s, off);
    ss += __shfl_xor(ss, off);
  }
  float mean = s * (1.f / 128.f);
  float var = ss * (1.f / 128.f) - mean * mean;
  float rs = rsqrtf(var + 1e-5f);
  float2 gg = ((const float2*)g)[lane];
  float2 bb = ((const float2*)b)[lane];
  float o0 = (v.x - mean) * rs * gg.x + bb.x;
  float o1 = (v.y - mean) * rs * gg.y + bb.y;
  unsigned int packed = ((unsigned int)f2bf(o1) << 16) | (unsigned int)f2bf(o0);
  ((unsigned int*)(out + (size_t)row * 128))[lane] = packed;
}

// ---------------- MFMA GEMM: out[m][n] (+)= sum_k A[m][k]*W[n][k] + bias[n] ----------------
// A bf16 [M][K] (M = gridDim.x*128), W bf16 [Ncols][K]. MODE 0: store bf16 (stride Ncols).
// MODE 1: outF[m*128+n] += v (fp32).
// Verified layouts (m89/m91/m120): A-frag A[m=lane&15][k=quad*8+j]; B-frag B[k=quad*8+j][n=lane&15];
// D reg r -> D[quad*4+r][lane&15].
template <int K, int MODE>
__global__ __launch_bounds__(256) void gemm_mfma(const unsigned short* __restrict__ A,
                                                 const unsigned short* __restrict__ W,
                                                 const float* __restrict__ bias,
                                                 unsigned short* __restrict__ outB,
                                                 float* __restrict__ outF, int Ncols) {
  const int tid = threadIdx.x;
  const int wave = tid >> 6, lane = tid & 63;
  const int wy = wave >> 1, wx = wave & 1;
  const int lr = lane & 15, lq = lane >> 4;
  const int m0 = blockIdx.x * 128 + wy * 64;
  const int n0 = blockIdx.y * 128 + wx * 64;

  f32x4 acc[4][4];
  #pragma unroll
  for (int i = 0; i < 4; ++i)
    #pragma unroll
    for (int j = 0; j < 4; ++j) acc[i][j] = f32x4{0.f, 0.f, 0.f, 0.f};

  const short8 zfrag = short8{0, 0, 0, 0, 0, 0, 0, 0};

  #pragma unroll
  for (int kk = 0; kk < K; kk += 32) {
    short8 af[4], bfq[4];
    #pragma unroll
    for (int i = 0; i < 4; ++i)
      af[i] = *(const short8*)(A + (size_t)(m0 + i * 16 + lr) * K + kk + lq * 8);
    #pragma unroll
    for (int j = 0; j < 4; ++j) {
      int wr = n0 + j * 16 + lr;
      bfq[j] = (wr < Ncols) ? *(const short8*)(W + (size_t)wr * K + kk + lq * 8) : zfrag;
    }
    #pragma unroll
    for (int i = 0; i < 4; ++i)
      #pragma unroll
      for (int j = 0; j < 4; ++j)
        acc[i][j] = __builtin_amdgcn_mfma_f32_16x16x32_bf16(af[i], bfq[j], acc[i][j], 0, 0, 0);
  }

  #pragma unroll
  for (int j = 0; j < 4; ++j) {
    int col = n0 + j * 16 + lr;
    if (col < Ncols) {
      float bb = bias[col];
      #pragma unroll
      for (int i = 0; i < 4; ++i) {
        #pragma unroll
        for (int r = 0; r < 4; ++r) {
          int row = m0 + i * 16 + lq * 4 + r;
          float v = acc[i][j][r] + bb;
          if (MODE == 0)
            outB[(size_t)row * Ncols + col] = f2bf(v);
          else
            outF[(size_t)row * 128 + col] += v;
        }
      }
    }
  }
}

// ---------------- grouped GRU scan over T=512 ----------------
// grid 256 blocks = (n, group-pair); 192 threads = (gl in 0..1) x (e in 0..95).
// xp (bf16) layout [(n*512+t)*384 + g*96 + e]; seq[n*512+t][128] += h_t.
__global__ __launch_bounds__(192) void gru_kernel(const unsigned short* __restrict__ xp,
                                                  const float* __restrict__ whh,
                                                  const float* __restrict__ bhh,
                                                  float* __restrict__ seq) {
  int blk = blockIdx.x;
  int n = blk >> 1, half = blk & 1;
  int tid = threadIdx.x;
  int gl = tid / 96, e = tid % 96;

  __shared__ __align__(16) float h_lds[64];
  __shared__ float gh[192], xs[192];

  float4 w4[8];
  #pragma unroll
  for (int u = 0; u < 8; ++u) w4[u] = *(const float4*)(whh + e * 32 + u * 4);
  float be = bhh[e];

  if (tid < 64) h_lds[tid] = 0.f;

  const unsigned short* xpu = xp + (size_t)n * 512 * 384 + half * 192 + tid;

  unsigned short xq[8];
  #pragma unroll
  for (int p = 0; p < 8; ++p) xq[p] = xpu[(size_t)p * 384];

  __syncthreads();

  for (int t0 = 0; t0 < 512; t0 += 8) {
    #pragma unroll
    for (int p = 0; p < 8; ++p) {
      int t = t0 + p;
      float xval = bf2f(xq[p]);
      if (t + 8 < 512) xq[p] = xpu[(size_t)(t + 8) * 384];  // prefetch depth 8

      float acc = be;
      #pragma unroll
      for (int u = 0; u < 8; ++u) {
        float4 h4 = *(const float4*)&h_lds[gl * 32 + u * 4];
        acc += w4[u].x * h4.x + w4[u].y * h4.y + w4[u].z * h4.z + w4[u].w * h4.w;
      }
      gh[tid] = acc;
      xs[tid] = xval;
      __syncthreads();

      if (e < 32) {
        int base = gl * 96, d = e;
        float xr = xs[base + d], xz = xs[base + 32 + d], xn = xs[base + 64 + d];
        float hr = gh[base + d], hz = gh[base + 32 + d], hn = gh[base + 64 + d];
        float r = 1.f / (1.f + __expf(-(xr + hr)));
        float z = 1.f / (1.f + __expf(-(xz + hz)));
        float nn = tanhf(xn + r * hn);
        float hold = h_lds[gl * 32 + d];
        float hnew = (1.f - z) * nn + z * hold;
        h_lds[gl * 32 + d] = hnew;
        seq[((size_t)(n * 512 + t)) * 128 + (half * 2 + gl) * 32 + d] += hnew;
      }
      __syncthreads();
    }
  }
}

// ---------------- windowed causal attention (scalar online softmax) ----------------
// grid (T/64=8, H=4, N=128), 128 threads = 32 q-pairs x 4 key-slices.
// qkv bf16 [n*512+t][384]: q @ h*32, k @ 128+h*32, v @ 256+h*32. out bf16 [n*512+t][128].
#define WCAP 164
__global__ __launch_bounds__(128) void attn_kernel(const unsigned short* __restrict__ qkv,
                                                   unsigned short* __restrict__ outp) {
  const int qbase = blockIdx.x * 64;
  const int h = blockIdx.y;
  const int n = blockIdx.z;
  const int tid = threadIdx.x;
  const int qp = tid >> 2, s = tid & 3;
  const int ws0 = max(0, qbase - 100);
  const int cnt = qbase + 64 - ws0;  // <= 164

  __shared__ unsigned int kl[WCAP * 20];
  __shared__ unsigned int vl[WCAP * 20];

  for (int i = tid; i < cnt * 16; i += 128) {
    int row = i >> 4, u = i & 15;
    size_t base = ((size_t)(n * 512 + ws0 + row)) * 384;
    kl[row * 20 + u] = ((const unsigned int*)(qkv + base + 128 + h * 32))[u];
    vl[row * 20 + u] = ((const unsigned int*)(qkv + base + 256 + h * 32))[u];
  }

  const int tqa = qbase + qp * 2, tqb = tqa + 1;
  float qv[2][32];
  {
    const unsigned int* qsa = (const unsigned int*)(qkv + ((size_t)(n * 512 + tqa)) * 384 + h * 32);
    const unsigned int* qsb = (const unsigned int*)(qkv + ((size_t)(n * 512 + tqb)) * 384 + h * 32);
    #pragma unroll
    for (int u = 0; u < 16; ++u) {
      unsigned int a = qsa[u], b = qsb[u];
      qv[0][2 * u] = bflo(a); qv[0][2 * u + 1] = bfhi(a);
      qv[1][2 * u] = bflo(b); qv[1][2 * u + 1] = bfhi(b);
    }
  }
  __syncthreads();

  float m[2] = {-INFINITY, -INFINITY}, l[2] = {0.f, 0.f};
  float o[2][32];
  #pragma unroll
  for (int d = 0; d < 32; ++d) { o[0][d] = 0.f; o[1][d] = 0.f; }

  const float scale = 0.17677669529663687f;  // 1/sqrt(32)
  const int iters = (cnt + 3) >> 2;

  for (int c = 0; c < iters; ++c) {
    int j = (c << 2) + s;
    int tk = ws0 + j;
    bool okv = (j < cnt);
    bool oka = okv && (tk <= tqa) && (tk + 100 >= tqa);
    bool okb = okv && (tk <= tqb) && (tk + 100 >= tqb);
    if (oka || okb) {
      float sa = 0.f, sb = 0.f;
      #pragma unroll
      for (int u = 0; u < 4; ++u) {
        uint4 kk = *(const uint4*)&kl[j * 20 + u * 4];
        float f0 = bflo(kk.x), f1 = bfhi(kk.x), f2 = bflo(kk.y), f3 = bfhi(kk.y);
        float f4 = bflo(kk.z), f5 = bfhi(kk.z), f6 = bflo(kk.w), f7 = bfhi(kk.w);
        int ee = u * 8;
        sa += qv[0][ee] * f0 + qv[0][ee + 1] * f1 + qv[0][ee + 2] * f2 + qv[0][ee + 3] * f3 +
              qv[0][ee + 4] * f4 + qv[0][ee + 5] * f5 + qv[0][ee + 6] * f6 + qv[0][ee + 7] * f7;
        sb += qv[1][ee] * f0 + qv[1][ee + 1] * f1 + qv[1][ee + 2] * f2 + qv[1][ee + 3] * f3 +
              qv[1][ee + 4] * f4 + qv[1][ee + 5] * f5 + qv[1][ee + 6] * f6 + qv[1][ee + 7] * f7;
      }
      sa *= scale; sb *= scale;
      float mna = oka ? fmaxf(m[0], sa) : m[0];
      float mnb = okb ? fmaxf(m[1], sb) : m[1];
      float ca = oka ? __expf(m[0] - mna) : 1.f;
      float cb = okb ? __expf(m[1] - mnb) : 1.f;
      float pa = oka ? __expf(sa - mna) : 0.f;
      float pb = okb ? __expf(sb - mnb) : 0.f;
      m[0] = mna; m[1] = mnb;
      l[0] = l[0] * ca + pa; l[1] = l[1] * cb + pb;
      #pragma unroll
      for (int u = 0; u < 4; ++u) {
        uint4 vvv = *(const uint4*)&vl[j * 20 + u * 4];
        float f0 = bflo(vvv.x), f1 = bfhi(vvv.x), f2 = bflo(vvv.y), f3 = bfhi(vvv.y);
        float f4 = bflo(vvv.z), f5 = bfhi(vvv.z), f6 = bflo(vvv.w), f7 = bfhi(vvv.w);
        int ee = u * 8;
        o[0][ee] = o[0][ee] * ca + pa * f0;       o[1][ee] = o[1][ee] * cb + pb * f0;
        o[0][ee + 1] = o[0][ee + 1] * ca + pa * f1; o[1][ee + 1] = o[1][ee + 1] * cb + pb * f1;
        o[0][ee + 2] = o[0][ee + 2] * ca + pa * f2; o[1][ee + 2] = o[1][ee + 2] * cb + pb * f2;
        o[0][ee + 3] = o[0][ee + 3] * ca + pa * f3; o[1][ee + 3] = o[1][ee + 3] * cb + pb * f3;
        o[0][ee + 4] = o[0][ee + 4] * ca + pa * f4; o[1][ee + 4] = o[1][ee + 4] * cb + pb * f4;
        o[0][ee + 5] = o[0][ee + 5] * ca + pa * f5; o[1][ee + 5] = o[1][ee + 5] * cb + pb * f5;
        o[0][ee + 6] = o[0][ee + 6] * ca + pa * f6; o[1][ee + 6] = o[1][ee + 6] * cb + pb * f6;
        o[0][ee + 7] = o[0][ee + 7] * ca + pa * f7; o[1][ee + 7] = o[1][ee + 7] * cb + pb * f7;
      }
    }
  }

  // merge the 4 key-slices (lanes 4*qp .. 4*qp+3, same wave) via shfl butterflies
  #pragma unroll
  for (int qi = 0; qi < 2; ++qi) {
    float mm = m[qi];
    mm = fmaxf(mm, __shfl_xor(mm, 1));
    mm = fmaxf(mm, __shfl_xor(mm, 2));
    float cr = __expf(m[qi] - mm);  // exp(-inf - finite) = 0 for empty slices
    float ll = l[qi] * cr;
    ll += __shfl_xor(ll, 1);
    ll += __shfl_xor(ll, 2);
    float rl = 1.f / ll;
    int tq = (qi == 0) ? tqa : tqb;
    size_t ob = ((size_t)(n * 512 + tq)) * 128 + h * 32;
    #pragma unroll
    for (int d = 0; d < 32; ++d) {
      float od = o[qi][d] * cr;
      od += __shfl_xor(od, 1);
      od += __shfl_xor(od, 2);
      if (s == 0) outp[ob + d] = f2bf(od * rl);
    }
  }
}

// ---------------- host launcher ----------------
extern "C" void kernel_launch(void* const* d_in, const int* in_sizes, int n_in,
                              void* d_out, int out_size, void* d_ws, size_t ws_size,
                              hipStream_t stream) {
  const float* x      = (const float*)d_in[0];
  const float* ln1_g  = (const float*)d_in[1];
  const float* ln1_b  = (const float*)d_in[2];
  const float* wih    = (const float*)d_in[3];
  const float* whh    = (const float*)d_in[4];
  const float* bih    = (const float*)d_in[5];
  const float* bhh    = (const float*)d_in[6];
  const float* ln2_g  = (const float*)d_in[7];
  const float* ln2_b  = (const float*)d_in[8];
  const float* inw    = (const float*)d_in[9];
  const float* inb    = (const float*)d_in[10];
  const float* outw   = (const float*)d_in[11];
  const float* outb   = (const float*)d_in[12];

  char* ws = (char*)d_ws;
  float*          seq   = (float*)ws;                             // 33,554,432 B
  unsigned short* tmpb  = (unsigned short*)(ws + 33554432);       // 16,777,216 B
  unsigned short* big   = (unsigned short*)(ws + 50331648);       // 50,331,648 B
  unsigned short* wih_b = (unsigned short*)(ws + 100663296);      // 3072 elems
  unsigned short* inw_b = wih_b + 3072;                           // 49152 elems
  unsigned short* outw_b = inw_b + 49152;                         // 16384 elems

  cvt_kernel<<<12, 256, 0, stream>>>(wih, wih_b, 3072);
  cvt_kernel<<<192, 256, 0, stream>>>(inw, inw_b, 49152);
  cvt_kernel<<<64, 256, 0, stream>>>(outw, outw_b, 16384);

  // x -> seq (residual stream)
  transpose_in_kernel<<<1024, 256, 0, stream>>>(x, seq);

  // ln1 -> tmpb (bf16), grouped view [262144][32]
  ln_kernel<<<16384, 256, 0, stream>>>(seq, ln1_g, ln1_b, tmpb);

  // GRU input projection: [262144][32] x [96][32]^T -> big [(n,t,g)][96]
  gemm_mfma<32, 0><<<dim3(2048, 1), 256, 0, stream>>>(tmpb, wih_b, bih, big, nullptr, 96);

  // GRU scan, seq += h_t
  gru_kernel<<<256, 192, 0, stream>>>(big, whh, bhh, seq);

  // ln2 -> tmpb
  ln_kernel<<<16384, 256, 0, stream>>>(seq, ln2_g, ln2_b, tmpb);

  // QKV projection: [65536][128] x [384][128]^T -> big [65536][384]
  gemm_mfma<128, 0><<<dim3(512, 3), 256, 0, stream>>>(tmpb, inw_b, inb, big, nullptr, 384);

  // attention -> tmpb (bf16)
  attn_kernel<<<dim3(8, 4, 128), 128, 0, stream>>>(big, tmpb);

  // out projection, seq += attn @ Wo^T + bo
  gemm_mfma<128, 1><<<dim3(512, 1), 256, 0, stream>>>(tmpb, outw_b, outb, nullptr, seq, 128);

  // seq -> d_out
  transpose_out_kernel<<<1024, 256, 0, stream>>>(seq, (float*)d_out);
}

// Round 2
// 664.882 us; speedup vs baseline: 1.2259x; 1.2259x over previous
//
#include <hip/hip_runtime.h>
#include <hip/hip_bf16.h>
#include <math.h>

// Problem constants: B=2, C=128, T=512, F=64 -> N=B*F=128 sequences, NT=65536 rows.
// GRU: G=4 groups, D=32, 3D=96. MHA: H=4 heads, Dh=32, window=100.
// Workspace layout (needs ~100.8 MB):
//   seq  fp32 [65536][128]  @ 0          (33,554,432 B)  residual stream
//   tmpb bf16 [65536][128]  @ 33554432   (16,777,216 B)  ln1/ln2/attn-out
//   big  bf16 [65536][384]  @ 50331648   (50,331,648 B)  xp (grouped: [(n,t,g)][96]) then qkv
//   wbuf bf16 weights       @ 100663296  (~137 KB)

typedef __attribute__((ext_vector_type(8))) short short8;
typedef __attribute__((ext_vector_type(4))) float f32x4;

__device__ __forceinline__ float bflo(unsigned int u) { return __uint_as_float(u << 16); }
__device__ __forceinline__ float bfhi(unsigned int u) { return __uint_as_float(u & 0xffff0000u); }
__device__ __forceinline__ float bf2f(unsigned short u) { return __uint_as_float(((unsigned int)u) << 16); }
__device__ __forceinline__ unsigned short f2bf(float f) {
  __hip_bfloat16 h = __float2bfloat16(f);
  return *reinterpret_cast<unsigned short*>(&h);
}

// ---------------- weight fp32 -> bf16 ----------------
__global__ void cvt_kernel(const float* __restrict__ s, unsigned short* __restrict__ d, int n) {
  int i = blockIdx.x * 256 + threadIdx.x;
  if (i < n) d[i] = f2bf(s[i]);
}

// ---------------- transpose x[B,C,T,F] -> seq[(b*64+f)][t][c] ----------------
__global__ __launch_bounds__(256) void transpose_in_kernel(const float* __restrict__ x, float* __restrict__ seq) {
  __shared__ float tile[128 * 65];
  int b = blockIdx.x >> 9;
  int t = blockIdx.x & 511;
  for (int i = threadIdx.x; i < 128 * 64; i += 256) {
    int c = i >> 6, f = i & 63;
    tile[c * 65 + f] = x[(((size_t)(b * 128 + c)) * 512 + t) * 64 + f];
  }
  __syncthreads();
  for (int i = threadIdx.x; i < 64 * 128; i += 256) {
    int f = i >> 7, c = i & 127;
    seq[(((size_t)(b * 64 + f)) * 512 + t) * 128 + c] = tile[c * 65 + f];
  }
}

__global__ __launch_bounds__(256) void transpose_out_kernel(const float* __restrict__ seq, float* __restrict__ out) {
  __shared__ float tile[128 * 65];
  int b = blockIdx.x >> 9;
  int t = blockIdx.x & 511;
  for (int i = threadIdx.x; i < 64 * 128; i += 256) {
    int f = i >> 7, c = i & 127;
    tile[c * 65 + f] = seq[(((size_t)(b * 64 + f)) * 512 + t) * 128 + c];
  }
  __syncthreads();
  for (int i = threadIdx.x; i < 128 * 64; i += 256) {
    int c = i >> 6, f = i & 63;
    out[(((size_t)(b * 128 + c)) * 512 + t) * 64 + f] = tile[c * 65 + f];
  }
}

// ---------------- layernorm over C=128, fp32 in -> bf16 out ----------------
__global__ __launch_bounds__(256) void ln_kernel(const float* __restrict__ in, const float* __restrict__ g,
                                                 const float* __restrict__ b, unsigned short* __restrict__ out) {
  int row = blockIdx.x * 4 + (threadIdx.x >> 6);
  int lane = threadIdx.x & 63;
  float2 v = ((const float2*)(in + (size_t)row * 128))[lane];
  float s = v.x + v.y, ss = v.x * v.x + v.y * v.y;
  #pragma unroll
  for (int off = 32; off > 0; off >>= 1) {
    s += __shfl_xor(s, off);
    ss += __shfl_xor(ss, off);
  }
  float mean = s * (1.f / 128.f);
  float var = ss * (1.f / 128.f) - mean * mean;
  float rs = rsqrtf(var + 1e-5f);
  float2 gg = ((const float2*)g)[lane];
  float2 bb = ((const float2*)b)[lane];
  float o0 = (v.x - mean) * rs * gg.x + bb.x;
  float o1 = (v.y - mean) * rs * gg.y + bb.y;
  unsigned int packed = ((unsigned int)f2bf(o1) << 16) | (unsigned int)f2bf(o0);
  ((unsigned int*)(out + (size_t)row * 128))[lane] = packed;
}

// ---------------- MFMA GEMM: out[m][n] (+)= sum_k A[m][k]*W[n][k] + bias[n] ----------------
// A bf16 [M][K] (M = gridDim.x*128), W bf16 [Ncols][K]. MODE 0: store bf16 (stride Ncols).
// MODE 1: outF[m*128+n] += v (fp32).
template <int K, int MODE>
__global__ __launch_bounds__(256) void gemm_mfma(const unsigned short* __restrict__ A,
                                                 const unsigned short* __restrict__ W,
                                                 const float* __restrict__ bias,
                                                 unsigned short* __restrict__ outB,
                                                 float* __restrict__ outF, int Ncols) {
  const int tid = threadIdx.x;
  const int wave = tid >> 6, lane = tid & 63;
  const int wy = wave >> 1, wx = wave & 1;
  const int lr = lane & 15, lq = lane >> 4;
  const int m0 = blockIdx.x * 128 + wy * 64;
  const int n0 = blockIdx.y * 128 + wx * 64;

  f32x4 acc[4][4];
  #pragma unroll
  for (int i = 0; i < 4; ++i)
    #pragma unroll
    for (int j = 0; j < 4; ++j) acc[i][j] = f32x4{0.f, 0.f, 0.f, 0.f};

  const short8 zfrag = short8{0, 0, 0, 0, 0, 0, 0, 0};

  #pragma unroll
  for (int kk = 0; kk < K; kk += 32) {
    short8 af[4], bfq[4];
    #pragma unroll
    for (int i = 0; i < 4; ++i)
      af[i] = *(const short8*)(A + (size_t)(m0 + i * 16 + lr) * K + kk + lq * 8);
    #pragma unroll
    for (int j = 0; j < 4; ++j) {
      int wr = n0 + j * 16 + lr;
      bfq[j] = (wr < Ncols) ? *(const short8*)(W + (size_t)wr * K + kk + lq * 8) : zfrag;
    }
    #pragma unroll
    for (int i = 0; i < 4; ++i)
      #pragma unroll
      for (int j = 0; j < 4; ++j)
        acc[i][j] = __builtin_amdgcn_mfma_f32_16x16x32_bf16(af[i], bfq[j], acc[i][j], 0, 0, 0);
  }

  #pragma unroll
  for (int j = 0; j < 4; ++j) {
    int col = n0 + j * 16 + lr;
    if (col < Ncols) {
      float bb = bias[col];
      #pragma unroll
      for (int i = 0; i < 4; ++i) {
        #pragma unroll
        for (int r = 0; r < 4; ++r) {
          int row = m0 + i * 16 + lq * 4 + r;
          float v = acc[i][j][r] + bb;
          if (MODE == 0)
            outB[(size_t)row * Ncols + col] = f2bf(v);
          else
            outF[(size_t)row * 128 + col] += v;
        }
      }
    }
  }
}

// ---------------- grouped GRU scan over T=512 — single-wave, register-resident ----------------
// 256 blocks x 64 threads (1 wave). Wave handles 2 chains (chain = n*4+g): lanes 0..31 = chain
// 2*blk (dim d=lane), lanes 32..63 = chain 2*blk+1. Each lane holds its 3 whh rows (r/z/n) in
// 96 VGPRs; h (32 floats per chain) lives in a 64-float LDS array, broadcast-read via
// ds_read_b128 (2-way broadcast = conflict-free). No cross-wave barriers on the serial path.
// xp/seq prefetched depth-4 so HBM latency stays off the recurrence.
__global__ __launch_bounds__(64) void gru_kernel(const unsigned short* __restrict__ xp,
                                                 const float* __restrict__ whh,
                                                 const float* __restrict__ bhh,
                                                 float* __restrict__ seq) {
  const int l = threadIdx.x;
  const int half = l >> 5, d = l & 31;
  const int blk = blockIdx.x;           // 0..255
  const int chain = blk * 2 + half;     // 0..511, chains 2b,2b+1 share n
  const int n = chain >> 2, g = chain & 3;
  const int g0 = (blk * 2) & 3;

  __shared__ __align__(16) float h_lds[64];
  h_lds[l] = 0.f;

  float wr[32], wz[32], wn[32];
  #pragma unroll
  for (int u = 0; u < 8; ++u) {
    float4 a = *(const float4*)(whh + (size_t)d * 32 + u * 4);
    float4 b = *(const float4*)(whh + (size_t)(32 + d) * 32 + u * 4);
    float4 c = *(const float4*)(whh + (size_t)(64 + d) * 32 + u * 4);
    wr[u * 4 + 0] = a.x; wr[u * 4 + 1] = a.y; wr[u * 4 + 2] = a.z; wr[u * 4 + 3] = a.w;
    wz[u * 4 + 0] = b.x; wz[u * 4 + 1] = b.y; wz[u * 4 + 2] = b.z; wz[u * 4 + 3] = b.w;
    wn[u * 4 + 0] = c.x; wn[u * 4 + 1] = c.y; wn[u * 4 + 2] = c.z; wn[u * 4 + 3] = c.w;
  }
  const float br = bhh[d], bz = bhh[32 + d], bn = bhh[64 + d];

  // xp row for this chain at step t: xp[((n*512+t)*4+g)*96 + {d, 32+d, 64+d}]
  const unsigned short* xb = xp + ((size_t)(n * 512) * 4 + g) * 96;
  // seq target: seq[(n*512+t)*128 + g0*32 + l]  (contiguous 64 floats per wave-step)
  float* sb = seq + (size_t)(n * 512) * 128 + g0 * 32 + l;

  unsigned short pr[4], pz[4], pn[4];
  float psv[4];
  #pragma unroll
  for (int p = 0; p < 4; ++p) {
    const unsigned short* xr_ = xb + (size_t)p * 384;
    pr[p] = xr_[d]; pz[p] = xr_[32 + d]; pn[p] = xr_[64 + d];
    psv[p] = sb[(size_t)p * 128];
  }

  float hprev = 0.f;

  for (int t0 = 0; t0 < 512; t0 += 4) {
    #pragma unroll
    for (int p = 0; p < 4; ++p) {
      const int t = t0 + p;
      __syncthreads();  // single-wave: pins LDS ordering, near-free

      float accr = br, accz = bz, accn = bn;
      #pragma unroll
      for (int u = 0; u < 8; ++u) {
        float4 h4 = *(const float4*)&h_lds[half * 32 + u * 4];
        accr = fmaf(wr[u * 4 + 0], h4.x, accr);
        accz = fmaf(wz[u * 4 + 0], h4.x, accz);
        accn = fmaf(wn[u * 4 + 0], h4.x, accn);
        accr = fmaf(wr[u * 4 + 1], h4.y, accr);
        accz = fmaf(wz[u * 4 + 1], h4.y, accz);
        accn = fmaf(wn[u * 4 + 1], h4.y, accn);
        accr = fmaf(wr[u * 4 + 2], h4.z, accr);
        accz = fmaf(wz[u * 4 + 2], h4.z, accz);
        accn = fmaf(wn[u * 4 + 2], h4.z, accn);
        accr = fmaf(wr[u * 4 + 3], h4.w, accr);
        accz = fmaf(wz[u * 4 + 3], h4.w, accz);
        accn = fmaf(wn[u * 4 + 3], h4.w, accn);
      }

      float xr = bf2f(pr[p]), xz = bf2f(pz[p]), xn = bf2f(pn[p]);
      float sv0 = psv[p];

      if (t + 4 < 512) {  // prefetch t+4 into slot p
        const unsigned short* xr_ = xb + (size_t)(t + 4) * 384;
        pr[p] = xr_[d]; pz[p] = xr_[32 + d]; pn[p] = xr_[64 + d];
        psv[p] = sb[(size_t)(t + 4) * 128];
      }

      float r = 1.f / (1.f + __expf(-(xr + accr)));
      float z = 1.f / (1.f + __expf(-(xz + accz)));
      float e2 = __expf(2.f * (xn + r * accn));
      float nn = 1.f - 2.f / (e2 + 1.f);  // tanh, saturates cleanly at +/-1
      float hnew = z * (hprev - nn) + nn;
      hprev = hnew;
      h_lds[l] = hnew;
      sb[(size_t)t * 128] = sv0 + hnew;
    }
  }
}

// ---------------- windowed causal attention (scalar online softmax) ----------------
// grid (T/64=8, H=4, N=128), 128 threads = 32 q-pairs x 4 key-slices.
// qkv bf16 [n*512+t][384]: q @ h*32, k @ 128+h*32, v @ 256+h*32. out bf16 [n*512+t][128].
#define WCAP 164
__global__ __launch_bounds__(128) void attn_kernel(const unsigned short* __restrict__ qkv,
                                                   unsigned short* __restrict__ outp) {
  const int qbase = blockIdx.x * 64;
  const int h = blockIdx.y;
  const int n = blockIdx.z;
  const int tid = threadIdx.x;
  const int qp = tid >> 2, s = tid & 3;
  const int ws0 = max(0, qbase - 100);
  const int cnt = qbase + 64 - ws0;  // <= 164

  __shared__ unsigned int kl[WCAP * 20];
  __shared__ unsigned int vl[WCAP * 20];

  for (int i = tid; i < cnt * 16; i += 128) {
    int row = i >> 4, u = i & 15;
    size_t base = ((size_t)(n * 512 + ws0 + row)) * 384;
    kl[row * 20 + u] = ((const unsigned int*)(qkv + base + 128 + h * 32))[u];
    vl[row * 20 + u] = ((const unsigned int*)(qkv + base + 256 + h * 32))[u];
  }

  const int tqa = qbase + qp * 2, tqb = tqa + 1;
  float qv[2][32];
  {
    const unsigned int* qsa = (const unsigned int*)(qkv + ((size_t)(n * 512 + tqa)) * 384 + h * 32);
    const unsigned int* qsb = (const unsigned int*)(qkv + ((size_t)(n * 512 + tqb)) * 384 + h * 32);
    #pragma unroll
    for (int u = 0; u < 16; ++u) {
      unsigned int a = qsa[u], b = qsb[u];
      qv[0][2 * u] = bflo(a); qv[0][2 * u + 1] = bfhi(a);
      qv[1][2 * u] = bflo(b); qv[1][2 * u + 1] = bfhi(b);
    }
  }
  __syncthreads();

  float m[2] = {-INFINITY, -INFINITY}, l[2] = {0.f, 0.f};
  float o[2][32];
  #pragma unroll
  for (int d = 0; d < 32; ++d) { o[0][d] = 0.f; o[1][d] = 0.f; }

  const float scale = 0.17677669529663687f;  // 1/sqrt(32)
  const int iters = (cnt + 3) >> 2;

  for (int c = 0; c < iters; ++c) {
    int j = (c << 2) + s;
    int tk = ws0 + j;
    bool okv = (j < cnt);
    bool oka = okv && (tk <= tqa) && (tk + 100 >= tqa);
    bool okb = okv && (tk <= tqb) && (tk + 100 >= tqb);
    if (oka || okb) {
      float sa = 0.f, sb = 0.f;
      #pragma unroll
      for (int u = 0; u < 4; ++u) {
        uint4 kk = *(const uint4*)&kl[j * 20 + u * 4];
        float f0 = bflo(kk.x), f1 = bfhi(kk.x), f2 = bflo(kk.y), f3 = bfhi(kk.y);
        float f4 = bflo(kk.z), f5 = bfhi(kk.z), f6 = bflo(kk.w), f7 = bfhi(kk.w);
        int ee = u * 8;
        sa += qv[0][ee] * f0 + qv[0][ee + 1] * f1 + qv[0][ee + 2] * f2 + qv[0][ee + 3] * f3 +
              qv[0][ee + 4] * f4 + qv[0][ee + 5] * f5 + qv[0][ee + 6] * f6 + qv[0][ee + 7] * f7;
        sb += qv[1][ee] * f0 + qv[1][ee + 1] * f1 + qv[1][ee + 2] * f2 + qv[1][ee + 3] * f3 +
              qv[1][ee + 4] * f4 + qv[1][ee + 5] * f5 + qv[1][ee + 6] * f6 + qv[1][ee + 7] * f7;
      }
      sa *= scale; sb *= scale;
      float mna = oka ? fmaxf(m[0], sa) : m[0];
      float mnb = okb ? fmaxf(m[1], sb) : m[1];
      float ca = oka ? __expf(m[0] - mna) : 1.f;
      float cb = okb ? __expf(m[1] - mnb) : 1.f;
      float pa = oka ? __expf(sa - mna) : 0.f;
      float pb = okb ? __expf(sb - mnb) : 0.f;
      m[0] = mna; m[1] = mnb;
      l[0] = l[0] * ca + pa; l[1] = l[1] * cb + pb;
      #pragma unroll
      for (int u = 0; u < 4; ++u) {
        uint4 vvv = *(const uint4*)&vl[j * 20 + u * 4];
        float f0 = bflo(vvv.x), f1 = bfhi(vvv.x), f2 = bflo(vvv.y), f3 = bfhi(vvv.y);
        float f4 = bflo(vvv.z), f5 = bfhi(vvv.z), f6 = bflo(vvv.w), f7 = bfhi(vvv.w);
        int ee = u * 8;
        o[0][ee] = o[0][ee] * ca + pa * f0;       o[1][ee] = o[1][ee] * cb + pb * f0;
        o[0][ee + 1] = o[0][ee + 1] * ca + pa * f1; o[1][ee + 1] = o[1][ee + 1] * cb + pb * f1;
        o[0][ee + 2] = o[0][ee + 2] * ca + pa * f2; o[1][ee + 2] = o[1][ee + 2] * cb + pb * f2;
        o[0][ee + 3] = o[0][ee + 3] * ca + pa * f3; o[1][ee + 3] = o[1][ee + 3] * cb + pb * f3;
        o[0][ee + 4] = o[0][ee + 4] * ca + pa * f4; o[1][ee + 4] = o[1][ee + 4] * cb + pb * f4;
        o[0][ee + 5] = o[0][ee + 5] * ca + pa * f5; o[1][ee + 5] = o[1][ee + 5] * cb + pb * f5;
        o[0][ee + 6] = o[0][ee + 6] * ca + pa * f6; o[1][ee + 6] = o[1][ee + 6] * cb + pb * f6;
        o[0][ee + 7] = o[0][ee + 7] * ca + pa * f7; o[1][ee + 7] = o[1][ee + 7] * cb + pb * f7;
      }
    }
  }

  // merge the 4 key-slices (lanes 4*qp .. 4*qp+3, same wave) via shfl butterflies
  #pragma unroll
  for (int qi = 0; qi < 2; ++qi) {
    float mm = m[qi];
    mm = fmaxf(mm, __shfl_xor(mm, 1));
    mm = fmaxf(mm, __shfl_xor(mm, 2));
    float cr = __expf(m[qi] - mm);  // exp(-inf - finite) = 0 for empty slices
    float ll = l[qi] * cr;
    ll += __shfl_xor(ll, 1);
    ll += __shfl_xor(ll, 2);
    float rl = 1.f / ll;
    int tq = (qi == 0) ? tqa : tqb;
    size_t ob = ((size_t)(n * 512 + tq)) * 128 + h * 32;
    #pragma unroll
    for (int d = 0; d < 32; ++d) {
      float od = o[qi][d] * cr;
      od += __shfl_xor(od, 1);
      od += __shfl_xor(od, 2);
      if (s == 0) outp[ob + d] = f2bf(od * rl);
    }
  }
}

// ---------------- host launcher ----------------
extern "C" void kernel_launch(void* const* d_in, const int* in_sizes, int n_in,
                              void* d_out, int out_size, void* d_ws, size_t ws_size,
                              hipStream_t stream) {
  const float* x      = (const float*)d_in[0];
  const float* ln1_g  = (const float*)d_in[1];
  const float* ln1_b  = (const float*)d_in[2];
  const float* wih    = (const float*)d_in[3];
  const float* whh    = (const float*)d_in[4];
  const float* bih    = (const float*)d_in[5];
  const float* bhh    = (const float*)d_in[6];
  const float* ln2_g  = (const float*)d_in[7];
  const float* ln2_b  = (const float*)d_in[8];
  const float* inw    = (const float*)d_in[9];
  const float* inb    = (const float*)d_in[10];
  const float* outw   = (const float*)d_in[11];
  const float* outb   = (const float*)d_in[12];

  char* ws = (char*)d_ws;
  float*          seq   = (float*)ws;                             // 33,554,432 B
  unsigned short* tmpb  = (unsigned short*)(ws + 33554432);       // 16,777,216 B
  unsigned short* big   = (unsigned short*)(ws + 50331648);       // 50,331,648 B
  unsigned short* wih_b = (unsigned short*)(ws + 100663296);      // 3072 elems
  unsigned short* inw_b = wih_b + 3072;                           // 49152 elems
  unsigned short* outw_b = inw_b + 49152;                         // 16384 elems

  cvt_kernel<<<12, 256, 0, stream>>>(wih, wih_b, 3072);
  cvt_kernel<<<192, 256, 0, stream>>>(inw, inw_b, 49152);
  cvt_kernel<<<64, 256, 0, stream>>>(outw, outw_b, 16384);

  // x -> seq (residual stream)
  transpose_in_kernel<<<1024, 256, 0, stream>>>(x, seq);

  // ln1 -> tmpb (bf16), grouped view [262144][32]
  ln_kernel<<<16384, 256, 0, stream>>>(seq, ln1_g, ln1_b, tmpb);

  // GRU input projection: [262144][32] x [96][32]^T -> big [(n,t,g)][96]
  gemm_mfma<32, 0><<<dim3(2048, 1), 256, 0, stream>>>(tmpb, wih_b, bih, big, nullptr, 96);

  // GRU scan, seq += h_t  (single-wave blocks, 2 chains/wave)
  gru_kernel<<<256, 64, 0, stream>>>(big, whh, bhh, seq);

  // ln2 -> tmpb
  ln_kernel<<<16384, 256, 0, stream>>>(seq, ln2_g, ln2_b, tmpb);

  // QKV projection: [65536][128] x [384][128]^T -> big [65536][384]
  gemm_mfma<128, 0><<<dim3(512, 3), 256, 0, stream>>>(tmpb, inw_b, inb, big, nullptr, 384);

  // attention -> tmpb (bf16)
  attn_kernel<<<dim3(8, 4, 128), 128, 0, stream>>>(big, tmpb);

  // out projection, seq += attn @ Wo^T + bo
  gemm_mfma<128, 1><<<dim3(512, 1), 256, 0, stream>>>(tmpb, outw_b, outb, nullptr, seq, 128);

  // seq -> d_out
  transpose_out_kernel<<<1024, 256, 0, stream>>>(seq, (float*)d_out);
}

// Round 3
// 627.333 us; speedup vs baseline: 1.2993x; 1.0599x over previous
//
#include <hip/hip_runtime.h>
#include <hip/hip_bf16.h>
#include <math.h>

// Problem constants: B=2, C=128, T=512, F=64 -> N=B*F=128 sequences, NT=65536 rows.
// GRU: G=4 groups, D=32, 3D=96. MHA: H=4 heads, Dh=32, window=100.
// Workspace layout (needs ~100.8 MB):
//   seq  fp32 [65536][128]  @ 0          (33,554,432 B)  residual stream
//   tmpb bf16 [65536][128]  @ 33554432   (16,777,216 B)  ln1/ln2/attn-out
//   big  bf16 [65536][384]  @ 50331648   (50,331,648 B)  xp (grouped: [(n,t,g)][96]) then qkv
//   wbuf bf16 weights       @ 100663296  (~137 KB)

typedef __attribute__((ext_vector_type(8))) short short8;
typedef __attribute__((ext_vector_type(4))) float f32x4;
typedef __attribute__((ext_vector_type(2))) float f32x2;

__device__ __forceinline__ float bflo(unsigned int u) { return __uint_as_float(u << 16); }
__device__ __forceinline__ float bfhi(unsigned int u) { return __uint_as_float(u & 0xffff0000u); }
__device__ __forceinline__ float bf2f(unsigned short u) { return __uint_as_float(((unsigned int)u) << 16); }
__device__ __forceinline__ unsigned short f2bf(float f) {
  __hip_bfloat16 h = __float2bfloat16(f);
  return *reinterpret_cast<unsigned short*>(&h);
}

// ---------------- weight fp32 -> bf16 ----------------
__global__ void cvt_kernel(const float* __restrict__ s, unsigned short* __restrict__ d, int n) {
  int i = blockIdx.x * 256 + threadIdx.x;
  if (i < n) d[i] = f2bf(s[i]);
}

// ---------------- transpose x[B,C,T,F] -> seq[(b*64+f)][t][c] ----------------
__global__ __launch_bounds__(256) void transpose_in_kernel(const float* __restrict__ x, float* __restrict__ seq) {
  __shared__ float tile[128 * 65];
  int b = blockIdx.x >> 9;
  int t = blockIdx.x & 511;
  for (int i = threadIdx.x; i < 128 * 64; i += 256) {
    int c = i >> 6, f = i & 63;
    tile[c * 65 + f] = x[(((size_t)(b * 128 + c)) * 512 + t) * 64 + f];
  }
  __syncthreads();
  for (int i = threadIdx.x; i < 64 * 128; i += 256) {
    int f = i >> 7, c = i & 127;
    seq[(((size_t)(b * 64 + f)) * 512 + t) * 128 + c] = tile[c * 65 + f];
  }
}

__global__ __launch_bounds__(256) void transpose_out_kernel(const float* __restrict__ seq, float* __restrict__ out) {
  __shared__ float tile[128 * 65];
  int b = blockIdx.x >> 9;
  int t = blockIdx.x & 511;
  for (int i = threadIdx.x; i < 64 * 128; i += 256) {
    int f = i >> 7, c = i & 127;
    tile[c * 65 + f] = seq[(((size_t)(b * 64 + f)) * 512 + t) * 128 + c];
  }
  __syncthreads();
  for (int i = threadIdx.x; i < 128 * 64; i += 256) {
    int c = i >> 6, f = i & 63;
    out[(((size_t)(b * 128 + c)) * 512 + t) * 64 + f] = tile[c * 65 + f];
  }
}

// ---------------- layernorm over C=128, fp32 in -> bf16 out ----------------
__global__ __launch_bounds__(256) void ln_kernel(const float* __restrict__ in, const float* __restrict__ g,
                                                 const float* __restrict__ b, unsigned short* __restrict__ out) {
  int row = blockIdx.x * 4 + (threadIdx.x >> 6);
  int lane = threadIdx.x & 63;
  float2 v = ((const float2*)(in + (size_t)row * 128))[lane];
  float s = v.x + v.y, ss = v.x * v.x + v.y * v.y;
  #pragma unroll
  for (int off = 32; off > 0; off >>= 1) {
    s += __shfl_xor(s, off);
    ss += __shfl_xor(ss, off);
  }
  float mean = s * (1.f / 128.f);
  float var = ss * (1.f / 128.f) - mean * mean;
  float rs = rsqrtf(var + 1e-5f);
  float2 gg = ((const float2*)g)[lane];
  float2 bb = ((const float2*)b)[lane];
  float o0 = (v.x - mean) * rs * gg.x + bb.x;
  float o1 = (v.y - mean) * rs * gg.y + bb.y;
  unsigned int packed = ((unsigned int)f2bf(o1) << 16) | (unsigned int)f2bf(o0);
  ((unsigned int*)(out + (size_t)row * 128))[lane] = packed;
}

// ---------------- MFMA GEMM: out[m][n] (+)= sum_k A[m][k]*W[n][k] + bias[n] ----------------
// A bf16 [M][K] (M = gridDim.x*128), W bf16 [Ncols][K]. MODE 0: store bf16 (stride Ncols).
// MODE 1: outF[m*128+n] += v (fp32).
template <int K, int MODE>
__global__ __launch_bounds__(256) void gemm_mfma(const unsigned short* __restrict__ A,
                                                 const unsigned short* __restrict__ W,
                                                 const float* __restrict__ bias,
                                                 unsigned short* __restrict__ outB,
                                                 float* __restrict__ outF, int Ncols) {
  const int tid = threadIdx.x;
  const int wave = tid >> 6, lane = tid & 63;
  const int wy = wave >> 1, wx = wave & 1;
  const int lr = lane & 15, lq = lane >> 4;
  const int m0 = blockIdx.x * 128 + wy * 64;
  const int n0 = blockIdx.y * 128 + wx * 64;

  f32x4 acc[4][4];
  #pragma unroll
  for (int i = 0; i < 4; ++i)
    #pragma unroll
    for (int j = 0; j < 4; ++j) acc[i][j] = f32x4{0.f, 0.f, 0.f, 0.f};

  const short8 zfrag = short8{0, 0, 0, 0, 0, 0, 0, 0};

  #pragma unroll
  for (int kk = 0; kk < K; kk += 32) {
    short8 af[4], bfq[4];
    #pragma unroll
    for (int i = 0; i < 4; ++i)
      af[i] = *(const short8*)(A + (size_t)(m0 + i * 16 + lr) * K + kk + lq * 8);
    #pragma unroll
    for (int j = 0; j < 4; ++j) {
      int wr = n0 + j * 16 + lr;
      bfq[j] = (wr < Ncols) ? *(const short8*)(W + (size_t)wr * K + kk + lq * 8) : zfrag;
    }
    #pragma unroll
    for (int i = 0; i < 4; ++i)
      #pragma unroll
      for (int j = 0; j < 4; ++j)
        acc[i][j] = __builtin_amdgcn_mfma_f32_16x16x32_bf16(af[i], bfq[j], acc[i][j], 0, 0, 0);
  }

  #pragma unroll
  for (int j = 0; j < 4; ++j) {
    int col = n0 + j * 16 + lr;
    if (col < Ncols) {
      float bb = bias[col];
      #pragma unroll
      for (int i = 0; i < 4; ++i) {
        #pragma unroll
        for (int r = 0; r < 4; ++r) {
          int row = m0 + i * 16 + lq * 4 + r;
          float v = acc[i][j][r] + bb;
          if (MODE == 0)
            outB[(size_t)row * Ncols + col] = f2bf(v);
          else
            outF[(size_t)row * 128 + col] += v;
        }
      }
    }
  }
}

// ---------------- grouped GRU scan over T=512 — single-wave, register-resident ----------------
// 256 blocks x 64 threads (1 wave). Wave handles 2 chains: lanes 0..31 = chain 2*blk (dim d =
// lane), lanes 32..63 = chain 2*blk+1. __launch_bounds__(64,1) gives the full 512-VGPR budget so
// the 96 whh weights per lane STAY in VGPRs (last round: VGPR_Count=80 proved they were being
// re-fetched from global every step — the 1500 cyc/step killer). No __syncthreads in the step
// loop: single-wave LDS ops execute in order; ordering pinned with wave_barrier + lgkmcnt(0)
// only, so the depth-4 global prefetch of xp/seq is never drained by a vmcnt(0).
__global__ __launch_bounds__(64, 1) void gru_kernel(const unsigned short* __restrict__ xp,
                                                    const float* __restrict__ whh,
                                                    const float* __restrict__ bhh,
                                                    float* __restrict__ seq) {
  const int l = threadIdx.x;
  const int half = l >> 5, d = l & 31;
  const int blk = blockIdx.x;           // 0..255
  const int chain = blk * 2 + half;     // chains 2b,2b+1 share n
  const int n = chain >> 2, g = chain & 3;
  const int g0 = (blk * 2) & 3;

  __shared__ __align__(16) float h_lds[64];
  h_lds[l] = 0.f;
  __builtin_amdgcn_wave_barrier();
  __builtin_amdgcn_s_waitcnt(0xC07F);  // lgkmcnt(0) only — init write retired

  // whh rows r/z/n for this lane's d, packed as float2 for v_pk_fma_f32
  f32x2 wr2[16], wz2[16], wn2[16];
  #pragma unroll
  for (int u = 0; u < 16; ++u) {
    float2 a = *(const float2*)(whh + (size_t)d * 32 + u * 2);
    float2 b = *(const float2*)(whh + (size_t)(32 + d) * 32 + u * 2);
    float2 c = *(const float2*)(whh + (size_t)(64 + d) * 32 + u * 2);
    wr2[u] = f32x2{a.x, a.y};
    wz2[u] = f32x2{b.x, b.y};
    wn2[u] = f32x2{c.x, c.y};
  }
  const float br = bhh[d], bz = bhh[32 + d], bn = bhh[64 + d];

  // xp row for this chain at step t: xp[((n*512+t)*4+g)*96 + {d, 32+d, 64+d}]
  const unsigned short* xb = xp + ((size_t)(n * 512) * 4 + g) * 96;
  // seq target: seq[(n*512+t)*128 + g0*32 + l]  (contiguous 64 floats per wave-step)
  float* sb = seq + (size_t)(n * 512) * 128 + g0 * 32 + l;

  unsigned short pr[4], pz[4], pn[4];
  float psv[4];
  #pragma unroll
  for (int p = 0; p < 4; ++p) {
    const unsigned short* xr_ = xb + (size_t)p * 384;
    pr[p] = xr_[d]; pz[p] = xr_[32 + d]; pn[p] = xr_[64 + d];
    psv[p] = sb[(size_t)p * 128];
  }

  float hprev = 0.f;

  for (int t0 = 0; t0 < 512; t0 += 4) {
    #pragma unroll
    for (int p = 0; p < 4; ++p) {
      const int t = t0 + p;

      f32x2 ar = f32x2{br, 0.f}, az = f32x2{bz, 0.f}, an = f32x2{bn, 0.f};
      const f32x2* hsrc = (const f32x2*)&h_lds[half * 32];
      #pragma unroll
      for (int u = 0; u < 16; ++u) {
        f32x2 h2 = hsrc[u];
        ar += wr2[u] * h2;
        az += wz2[u] * h2;
        an += wn2[u] * h2;
      }
      float accr = ar.x + ar.y, accz = az.x + az.y, accn = an.x + an.y;

      float xr = bf2f(pr[p]), xz = bf2f(pz[p]), xn = bf2f(pn[p]);
      float sv0 = psv[p];

      if (t + 4 < 512) {  // prefetch t+4 into slot p (stays in flight — no vmcnt drain)
        const unsigned short* xr_ = xb + (size_t)(t + 4) * 384;
        pr[p] = xr_[d]; pz[p] = xr_[32 + d]; pn[p] = xr_[64 + d];
        psv[p] = sb[(size_t)(t + 4) * 128];
      }

      float r = 1.f / (1.f + __expf(-(xr + accr)));
      float z = 1.f / (1.f + __expf(-(xz + accz)));
      float e2 = __expf(2.f * (xn + r * accn));
      float nn = 1.f - 2.f / (e2 + 1.f);  // tanh, saturates cleanly at +/-1
      float hnew = z * (hprev - nn) + nn;
      hprev = hnew;

      __builtin_amdgcn_wave_barrier();     // keep write after this step's reads
      h_lds[l] = hnew;
      __builtin_amdgcn_s_waitcnt(0xC07F);  // lgkmcnt(0) — write retired before next reads
      __builtin_amdgcn_wave_barrier();     // keep next step's reads after the write

      sb[(size_t)t * 128] = sv0 + hnew;
    }
  }
}

// ---------------- windowed causal attention (scalar online softmax) ----------------
// grid (T/64=8, H=4, N=128), 128 threads = 32 q-pairs x 4 key-slices.
// qkv bf16 [n*512+t][384]: q @ h*32, k @ 128+h*32, v @ 256+h*32. out bf16 [n*512+t][128].
#define WCAP 164
__global__ __launch_bounds__(128) void attn_kernel(const unsigned short* __restrict__ qkv,
                                                   unsigned short* __restrict__ outp) {
  const int qbase = blockIdx.x * 64;
  const int h = blockIdx.y;
  const int n = blockIdx.z;
  const int tid = threadIdx.x;
  const int qp = tid >> 2, s = tid & 3;
  const int ws0 = max(0, qbase - 100);
  const int cnt = qbase + 64 - ws0;  // <= 164

  __shared__ unsigned int kl[WCAP * 20];
  __shared__ unsigned int vl[WCAP * 20];

  for (int i = tid; i < cnt * 16; i += 128) {
    int row = i >> 4, u = i & 15;
    size_t base = ((size_t)(n * 512 + ws0 + row)) * 384;
    kl[row * 20 + u] = ((const unsigned int*)(qkv + base + 128 + h * 32))[u];
    vl[row * 20 + u] = ((const unsigned int*)(qkv + base + 256 + h * 32))[u];
  }

  const int tqa = qbase + qp * 2, tqb = tqa + 1;
  float qv[2][32];
  {
    const unsigned int* qsa = (const unsigned int*)(qkv + ((size_t)(n * 512 + tqa)) * 384 + h * 32);
    const unsigned int* qsb = (const unsigned int*)(qkv + ((size_t)(n * 512 + tqb)) * 384 + h * 32);
    #pragma unroll
    for (int u = 0; u < 16; ++u) {
      unsigned int a = qsa[u], b = qsb[u];
      qv[0][2 * u] = bflo(a); qv[0][2 * u + 1] = bfhi(a);
      qv[1][2 * u] = bflo(b); qv[1][2 * u + 1] = bfhi(b);
    }
  }
  __syncthreads();

  float m[2] = {-INFINITY, -INFINITY}, l[2] = {0.f, 0.f};
  float o[2][32];
  #pragma unroll
  for (int d = 0; d < 32; ++d) { o[0][d] = 0.f; o[1][d] = 0.f; }

  const float scale = 0.17677669529663687f;  // 1/sqrt(32)
  const int iters = (cnt + 3) >> 2;

  for (int c = 0; c < iters; ++c) {
    int j = (c << 2) + s;
    int tk = ws0 + j;
    bool okv = (j < cnt);
    bool oka = okv && (tk <= tqa) && (tk + 100 >= tqa);
    bool okb = okv && (tk <= tqb) && (tk + 100 >= tqb);
    if (oka || okb) {
      float sa = 0.f, sb = 0.f;
      #pragma unroll
      for (int u = 0; u < 4; ++u) {
        uint4 kk = *(const uint4*)&kl[j * 20 + u * 4];
        float f0 = bflo(kk.x), f1 = bfhi(kk.x), f2 = bflo(kk.y), f3 = bfhi(kk.y);
        float f4 = bflo(kk.z), f5 = bfhi(kk.z), f6 = bflo(kk.w), f7 = bfhi(kk.w);
        int ee = u * 8;
        sa += qv[0][ee] * f0 + qv[0][ee + 1] * f1 + qv[0][ee + 2] * f2 + qv[0][ee + 3] * f3 +
              qv[0][ee + 4] * f4 + qv[0][ee + 5] * f5 + qv[0][ee + 6] * f6 + qv[0][ee + 7] * f7;
        sb += qv[1][ee] * f0 + qv[1][ee + 1] * f1 + qv[1][ee + 2] * f2 + qv[1][ee + 3] * f3 +
              qv[1][ee + 4] * f4 + qv[1][ee + 5] * f5 + qv[1][ee + 6] * f6 + qv[1][ee + 7] * f7;
      }
      sa *= scale; sb *= scale;
      float mna = oka ? fmaxf(m[0], sa) : m[0];
      float mnb = okb ? fmaxf(m[1], sb) : m[1];
      float ca = oka ? __expf(m[0] - mna) : 1.f;
      float cb = okb ? __expf(m[1] - mnb) : 1.f;
      float pa = oka ? __expf(sa - mna) : 0.f;
      float pb = okb ? __expf(sb - mnb) : 0.f;
      m[0] = mna; m[1] = mnb;
      l[0] = l[0] * ca + pa; l[1] = l[1] * cb + pb;
      #pragma unroll
      for (int u = 0; u < 4; ++u) {
        uint4 vvv = *(const uint4*)&vl[j * 20 + u * 4];
        float f0 = bflo(vvv.x), f1 = bfhi(vvv.x), f2 = bflo(vvv.y), f3 = bfhi(vvv.y);
        float f4 = bflo(vvv.z), f5 = bfhi(vvv.z), f6 = bflo(vvv.w), f7 = bfhi(vvv.w);
        int ee = u * 8;
        o[0][ee] = o[0][ee] * ca + pa * f0;       o[1][ee] = o[1][ee] * cb + pb * f0;
        o[0][ee + 1] = o[0][ee + 1] * ca + pa * f1; o[1][ee + 1] = o[1][ee + 1] * cb + pb * f1;
        o[0][ee + 2] = o[0][ee + 2] * ca + pa * f2; o[1][ee + 2] = o[1][ee + 2] * cb + pb * f2;
        o[0][ee + 3] = o[0][ee + 3] * ca + pa * f3; o[1][ee + 3] = o[1][ee + 3] * cb + pb * f3;
        o[0][ee + 4] = o[0][ee + 4] * ca + pa * f4; o[1][ee + 4] = o[1][ee + 4] * cb + pb * f4;
        o[0][ee + 5] = o[0][ee + 5] * ca + pa * f5; o[1][ee + 5] = o[1][ee + 5] * cb + pb * f5;
        o[0][ee + 6] = o[0][ee + 6] * ca + pa * f6; o[1][ee + 6] = o[1][ee + 6] * cb + pb * f6;
        o[0][ee + 7] = o[0][ee + 7] * ca + pa * f7; o[1][ee + 7] = o[1][ee + 7] * cb + pb * f7;
      }
    }
  }

  // merge the 4 key-slices (lanes 4*qp .. 4*qp+3, same wave) via shfl butterflies
  #pragma unroll
  for (int qi = 0; qi < 2; ++qi) {
    float mm = m[qi];
    mm = fmaxf(mm, __shfl_xor(mm, 1));
    mm = fmaxf(mm, __shfl_xor(mm, 2));
    float cr = __expf(m[qi] - mm);  // exp(-inf - finite) = 0 for empty slices
    float ll = l[qi] * cr;
    ll += __shfl_xor(ll, 1);
    ll += __shfl_xor(ll, 2);
    float rl = 1.f / ll;
    int tq = (qi == 0) ? tqa : tqb;
    size_t ob = ((size_t)(n * 512 + tq)) * 128 + h * 32;
    #pragma unroll
    for (int d = 0; d < 32; ++d) {
      float od = o[qi][d] * cr;
      od += __shfl_xor(od, 1);
      od += __shfl_xor(od, 2);
      if (s == 0) outp[ob + d] = f2bf(od * rl);
    }
  }
}

// ---------------- host launcher ----------------
extern "C" void kernel_launch(void* const* d_in, const int* in_sizes, int n_in,
                              void* d_out, int out_size, void* d_ws, size_t ws_size,
                              hipStream_t stream) {
  const float* x      = (const float*)d_in[0];
  const float* ln1_g  = (const float*)d_in[1];
  const float* ln1_b  = (const float*)d_in[2];
  const float* wih    = (const float*)d_in[3];
  const float* whh    = (const float*)d_in[4];
  const float* bih    = (const float*)d_in[5];
  const float* bhh    = (const float*)d_in[6];
  const float* ln2_g  = (const float*)d_in[7];
  const float* ln2_b  = (const float*)d_in[8];
  const float* inw    = (const float*)d_in[9];
  const float* inb    = (const float*)d_in[10];
  const float* outw   = (const float*)d_in[11];
  const float* outb   = (const float*)d_in[12];

  char* ws = (char*)d_ws;
  float*          seq   = (float*)ws;                             // 33,554,432 B
  unsigned short* tmpb  = (unsigned short*)(ws + 33554432);       // 16,777,216 B
  unsigned short* big   = (unsigned short*)(ws + 50331648);       // 50,331,648 B
  unsigned short* wih_b = (unsigned short*)(ws + 100663296);      // 3072 elems
  unsigned short* inw_b = wih_b + 3072;                           // 49152 elems
  unsigned short* outw_b = inw_b + 49152;                         // 16384 elems

  cvt_kernel<<<12, 256, 0, stream>>>(wih, wih_b, 3072);
  cvt_kernel<<<192, 256, 0, stream>>>(inw, inw_b, 49152);
  cvt_kernel<<<64, 256, 0, stream>>>(outw, outw_b, 16384);

  // x -> seq (residual stream)
  transpose_in_kernel<<<1024, 256, 0, stream>>>(x, seq);

  // ln1 -> tmpb (bf16), grouped view [262144][32]
  ln_kernel<<<16384, 256, 0, stream>>>(seq, ln1_g, ln1_b, tmpb);

  // GRU input projection: [262144][32] x [96][32]^T -> big [(n,t,g)][96]
  gemm_mfma<32, 0><<<dim3(2048, 1), 256, 0, stream>>>(tmpb, wih_b, bih, big, nullptr, 96);

  // GRU scan, seq += h_t  (single-wave blocks, 2 chains/wave)
  gru_kernel<<<256, 64, 0, stream>>>(big, whh, bhh, seq);

  // ln2 -> tmpb
  ln_kernel<<<16384, 256, 0, stream>>>(seq, ln2_g, ln2_b, tmpb);

  // QKV projection: [65536][128] x [384][128]^T -> big [65536][384]
  gemm_mfma<128, 0><<<dim3(512, 3), 256, 0, stream>>>(tmpb, inw_b, inb, big, nullptr, 384);

  // attention -> tmpb (bf16)
  attn_kernel<<<dim3(8, 4, 128), 128, 0, stream>>>(big, tmpb);

  // out projection, seq += attn @ Wo^T + bo
  gemm_mfma<128, 1><<<dim3(512, 1), 256, 0, stream>>>(tmpb, outw_b, outb, nullptr, seq, 128);

  // seq -> d_out
  transpose_out_kernel<<<1024, 256, 0, stream>>>(seq, (float*)d_out);
}